// Round 11
// baseline (7299.766 us; speedup 1.0000x reference)
//
#include <hip/hip_runtime.h>

typedef unsigned short u16;

__device__ __forceinline__ float bf2f(u16 u) {
  union { unsigned int i; float f; } x;
  x.i = ((unsigned int)u) << 16;
  return x.f;
}
__device__ __forceinline__ u16 f2bf(float f) {
  union { float f; unsigned int i; } u;
  u.f = f;
  unsigned int r = u.i + 0x7fffu + ((u.i >> 16) & 1u);
  return (u16)(r >> 16);
}

static inline int nblk3(long long n) { return (int)((n + 255) / 256); }

// identifier-named symbol (also used as fp32 zero-fill)
__global__ void HeteroGraphSAGE_52931176955955_kernel(float* p, long long n) {
  long long i = (long long)blockIdx.x * 256 + threadIdx.x;
  if (i < n) p[i] = 0.0f;
}

__global__ void g_copy_f32(const float* s, float* d, long long n) {
  long long i = (long long)blockIdx.x * 256 + threadIdx.x;
  if (i < n) d[i] = s[i];
}

// ---------- scatter into agg rows [d0,d1): 1 thread per (edge,col) ----------
__global__ void g_scat(const void* xs, int src_bf, const int* e, int E,
                       float* agg, float* cnt, int d0, int d1) {
  long long i = (long long)blockIdx.x * 256 + threadIdx.x;
  if (i >= (long long)E * 128) return;
  int w = (int)(i >> 7);
  int d = e[E + w];
  if (d < d0 || d >= d1) return;
  int c = (int)(i & 127);
  int s = e[w];
  float v = src_bf ? bf2f(((const u16*)xs)[(size_t)s * 128 + c])
                   : ((const float*)xs)[(size_t)s * 128 + c];
  atomicAdd(agg + (size_t)(d - d0) * 128 + c, v);
  if (c == 0) atomicAdd(cnt + (d - d0), 1.0f);
}

// ---------- fused SAGE GEMM over rows [d0,d1) ----------
// out[r,c] (+)= sum_k (agg[r,k]/max(cnt,1))*Wl[k,c] (+ root[r,k]*Wr[k,c]) + bias[c]
// W/bias fp32; root fp32 or bf16 or null; out fp32 or bf16.
__global__ void g_gemm(const float* agg, const float* cnt,
                       const void* root, int root_bf,
                       const float* Wl, const float* Wr, const float* bias,
                       void* out, int out_bf, int d0, int d1, int accum) {
  __shared__ float sm[8][128];
  __shared__ float sx[8][128];
  int tid = threadIdx.x;
  int r0 = d0 + blockIdx.x * 8;

  for (int i = tid; i < 1024; i += 256) {
    int rr = i >> 7, k = i & 127;
    int row = r0 + rr;
    float mv = 0.f, xv = 0.f;
    if (row < d1) {
      float inv = 1.0f / fmaxf(cnt[row - d0], 1.0f);
      mv = agg[(size_t)(row - d0) * 128 + k] * inv;
      if (root)
        xv = root_bf ? bf2f(((const u16*)root)[(size_t)row * 128 + k])
                     : ((const float*)root)[(size_t)row * 128 + k];
    }
    sm[rr][k] = mv;
    sx[rr][k] = xv;
  }
  __syncthreads();

  int c  = tid & 127;
  int rg = (tid >> 7) * 4;
  float a0 = 0.f, a1 = 0.f, a2 = 0.f, a3 = 0.f;
  if (root) {
    for (int k = 0; k < 128; ++k) {
      float wl = Wl[k * 128 + c];
      float wr = Wr[k * 128 + c];
      a0 += sm[rg + 0][k] * wl + sx[rg + 0][k] * wr;
      a1 += sm[rg + 1][k] * wl + sx[rg + 1][k] * wr;
      a2 += sm[rg + 2][k] * wl + sx[rg + 2][k] * wr;
      a3 += sm[rg + 3][k] * wl + sx[rg + 3][k] * wr;
    }
  } else {
    for (int k = 0; k < 128; ++k) {
      float wl = Wl[k * 128 + c];
      a0 += sm[rg + 0][k] * wl;
      a1 += sm[rg + 1][k] * wl;
      a2 += sm[rg + 2][k] * wl;
      a3 += sm[rg + 3][k] * wl;
    }
  }
  float bb = bias[c];
  float acc[4] = {a0, a1, a2, a3};
  for (int j = 0; j < 4; ++j) {
    int row = r0 + rg + j;
    if (row < d1) {
      size_t o = (size_t)row * 128 + c;
      float v = acc[j] + bb;
      if (out_bf) {
        u16* ob = (u16*)out;
        if (accum) v += bf2f(ob[o]);
        ob[o] = f2bf(v);
      } else {
        float* of = (float*)out;
        if (accum) v += of[o];
        of[o] = v;
      }
    }
  }
}

// ---------- BN (training-mode stats over relu(x)), in-place ----------
__global__ void g_bn_stats(const void* x, int isbf, int N, float* stats) {
  __shared__ float ls[1024];
  __shared__ float ls2[1024];
  int col = blockIdx.x;   // 0..127
  int tid = threadIdx.x;  // 0..1023
  float s = 0.f, s2 = 0.f;
  for (int r = tid; r < N; r += 1024) {
    float v = isbf ? bf2f(((const u16*)x)[(size_t)r * 128 + col])
                   : ((const float*)x)[(size_t)r * 128 + col];
    v = fmaxf(v, 0.f);
    s += v;
    s2 += v * v;
  }
  ls[tid] = s;
  ls2[tid] = s2;
  __syncthreads();
  for (int d = 512; d > 0; d >>= 1) {
    if (tid < d) { ls[tid] += ls[tid + d]; ls2[tid] += ls2[tid + d]; }
    __syncthreads();
  }
  if (tid == 0) { stats[col] = ls[0]; stats[128 + col] = ls2[0]; }
}

__global__ void g_bn_finalize(const float* stats, const float* g, const float* b,
                              float invN, float* scsh) {
  int c = threadIdx.x;  // 128
  float m  = stats[c] * invN;
  float v  = stats[128 + c] * invN - m * m;
  float sc = rsqrtf(v + 1e-5f) * g[c];
  scsh[c] = sc;
  scsh[128 + c] = b[c] - m * sc;
}

__global__ void g_bn_apply(void* x, int isbf, const float* scsh, long long n) {
  long long i = (long long)blockIdx.x * 256 + threadIdx.x;
  if (i >= n) return;
  int c = (int)(i & 127);
  if (isbf) {
    u16* xb = (u16*)x;
    float v = fmaxf(bf2f(xb[i]), 0.f) * scsh[c] + scsh[128 + c];
    xb[i] = f2bf(v);
  } else {
    float* xf = (float*)x;
    float v = fmaxf(xf[i], 0.f) * scsh[c] + scsh[128 + c];
    xf[i] = v;
  }
}

// ---------- host helpers ----------
#define CHUNK3 100000

static void sage_v3(const void* src, int src_bf, const int* e, int E,
                    const void* root, int root_bf,
                    const float* Wl, const float* Wr, const float* bias,
                    int ndst, void* out, int out_bf, int accum,
                    float* agg, float* cnt, hipStream_t st) {
  for (int d0 = 0; d0 < ndst; d0 += CHUNK3) {
    int d1 = d0 + CHUNK3; if (d1 > ndst) d1 = ndst;
    int nr = d1 - d0;
    long long na = (long long)nr * 128;
    HeteroGraphSAGE_52931176955955_kernel<<<nblk3(na), 256, 0, st>>>(agg, na);
    HeteroGraphSAGE_52931176955955_kernel<<<nblk3(nr), 256, 0, st>>>(cnt, nr);
    g_scat<<<nblk3((long long)E * 128), 256, 0, st>>>(src, src_bf, e, E, agg, cnt, d0, d1);
    g_gemm<<<(nr + 7) / 8, 256, 0, st>>>(agg, cnt, root, root_bf,
                                         Wl, Wr, bias, out, out_bf, d0, d1, accum);
  }
}

static void bn_v3(void* h, int isbf, int n, const float* g, const float* b,
                  float* stats, float* scsh, hipStream_t st) {
  g_bn_stats<<<128, 1024, 0, st>>>(h, isbf, n, stats);
  g_bn_finalize<<<1, 128, 0, st>>>(stats, g, b, 1.0f / (float)n, scsh);
  long long ne = (long long)n * 128;
  g_bn_apply<<<nblk3(ne), 256, 0, st>>>(h, isbf, scsh, ne);
}

extern "C" void kernel_launch(void* const* d_in, const int* in_sizes, int n_in,
                              void* d_out, int out_size, void* d_ws, size_t ws_size,
                              hipStream_t stream) {
  // per reference dtypes: features/weights fp32, edges int32, OUTPUT fp32
  const float* x_paper  = (const float*)d_in[0];
  const float* x_author = (const float*)d_in[1];
  const int* e_pp = (const int*)d_in[3];
  const int* e_pa = (const int*)d_in[4];
  const int* e_ap = (const int*)d_in[5];
  const int* e_ai = (const int*)d_in[6];
  const int* e_ia = (const int*)d_in[7];
  const float* Wl  = (const float*)d_in[8];
  const float* bL  = (const float*)d_in[9];
  const float* Wr  = (const float*)d_in[10];
  const float* bng = (const float*)d_in[11];
  const float* bnb = (const float*)d_in[12];

  const int NP = in_sizes[0] / 128;
  const int NA = in_sizes[1] / 128;
  const int NI = in_sizes[2] / 128;
  const int Epp = in_sizes[3] / 2;
  const int Epa = in_sizes[4] / 2;
  const int Eap = in_sizes[5] / 2;
  const int Eai = in_sizes[6] / 2;
  const int Eia = in_sizes[7] / 2;

  // ws (~141 MB): h_p1/h_a1 bf16 | stats | scsh | cnt | agg (CHUNK3 x 128 f32)
  char* ws = (char*)d_ws;
  size_t off = 0;
  u16* h_p1 = (u16*)(ws + off);      off += (size_t)NP * 256;
  u16* h_a1 = (u16*)(ws + off);      off += (size_t)NA * 256;
  float* stats = (float*)(ws + off); off += 1024;
  float* scsh  = (float*)(ws + off); off += 1024;
  float* cnt   = (float*)(ws + off); off += (size_t)CHUNK3 * 4;
  float* agg   = (float*)(ws + off);
  // i1 root copy: agg rows [NI, 2*NI) — disjoint from i2's pass (rows < NI)
  float* i1c = agg + (size_t)NI * 128;

  // d_out is fp32: p2 | a2 | i2. Layer-0/1 hiddens live in these regions (fp32).
  float* outp = (float*)d_out;
  float* outa = outp + (size_t)NP * 128;
  float* outi = outa + (size_t)NA * 128;
  float* h_p0 = outp;
  float* h_a0 = outa;
  float* h_i1 = outi;

  // ---- Layer 0 (src/root fp32, out fp32 in d_out regions) ----
  sage_v3(x_paper, 0, e_pp, Epp, x_paper, 0, Wl + 0 * 16384, Wr + 0 * 16384,
          bL + 0 * 128, NP, h_p0, 0, 0, agg, cnt, stream);
  bn_v3(h_p0, 0, NP, bng + 0 * 128, bnb + 0 * 128, stats, scsh, stream);
  sage_v3(x_paper, 0, e_pa, Epa, x_author, 0, Wl + 1 * 16384, Wr + 1 * 16384,
          bL + 1 * 128, NA, h_a0, 0, 0, agg, cnt, stream);
  bn_v3(h_a0, 0, NA, bng + 1 * 128, bnb + 1 * 128, stats, scsh, stream);

  // ---- Layer 1 (src/root fp32 hiddens; h_p1/h_a1 bf16 in ws; h_i1 fp32 in outi) ----
  sage_v3(h_p0, 0, e_pp, Epp, h_p0, 0, Wl + 2 * 16384, Wr + 2 * 16384,
          bL + 2 * 128, NP, h_p1, 1, 0, agg, cnt, stream);
  sage_v3(h_a0, 0, e_ap, Eap, h_p0, 0, Wl + 4 * 16384, Wr + 4 * 16384,
          bL + 4 * 128, NP, h_p1, 1, 1, agg, cnt, stream);
  bn_v3(h_p1, 1, NP, bng + 2 * 128, bnb + 2 * 128, stats, scsh, stream);
  sage_v3(h_p0, 0, e_pa, Epa, h_a0, 0, Wl + 3 * 16384, Wr + 3 * 16384,
          bL + 3 * 128, NA, h_a1, 1, 0, agg, cnt, stream);
  bn_v3(h_a1, 1, NA, bng + 3 * 128, bnb + 3 * 128, stats, scsh, stream);
  sage_v3(h_a0, 0, e_ai, Eai, (const void*)0, 0, Wl + 5 * 16384, Wr + 5 * 16384,
          bL + 5 * 128, NI, h_i1, 0, 0, agg, cnt, stream);
  bn_v3(h_i1, 0, NI, bng + 4 * 128, bnb + 4 * 128, stats, scsh, stream);

  // ---- Layer 2 (out fp32 into d_out; h_p0/h_a0 dead; h_i1 consumed before outi) ----
  sage_v3(h_p1, 1, e_pp, Epp, h_p1, 1, Wl + 6 * 16384, Wr + 6 * 16384,
          bL + 6 * 128, NP, outp, 0, 0, agg, cnt, stream);
  sage_v3(h_a1, 1, e_ap, Eap, h_p1, 1, Wl + 8 * 16384, Wr + 8 * 16384,
          bL + 8 * 128, NP, outp, 0, 1, agg, cnt, stream);
  sage_v3(h_p1, 1, e_pa, Epa, h_a1, 1, Wl + 7 * 16384, Wr + 7 * 16384,
          bL + 7 * 128, NA, outa, 0, 0, agg, cnt, stream);
  sage_v3(h_i1, 0, e_ia, Eia, h_a1, 1, Wl + 10 * 16384, Wr + 10 * 16384,
          bL + 10 * 128, NA, outa, 0, 1, agg, cnt, stream);
  // i2: copy root out of its own output region, then compute
  g_copy_f32<<<nblk3((long long)NI * 128), 256, 0, stream>>>(h_i1, i1c, (long long)NI * 128);
  sage_v3(h_a1, 1, e_ai, Eai, i1c, 0, Wl + 9 * 16384, Wr + 9 * 16384,
          bL + 9 * 128, NI, outi, 0, 0, agg, cnt, stream);

  (void)n_in; (void)ws_size; (void)out_size;
}

// Round 12
// 5009.091 us; speedup vs baseline: 1.4573x; 1.4573x over previous
//
#include <hip/hip_runtime.h>

typedef unsigned short u16;

__device__ __forceinline__ float bf2f(u16 u) {
  union { unsigned int i; float f; } x;
  x.i = ((unsigned int)u) << 16;
  return x.f;
}
__device__ __forceinline__ u16 f2bf(float f) {
  union { float f; unsigned int i; } u;
  u.f = f;
  unsigned int r = u.i + 0x7fffu + ((u.i >> 16) & 1u);
  return (u16)(r >> 16);
}

static inline int nblk4(long long n) { return (int)((n + 255) / 256); }

// identifier-named symbol; also the generic zero-fill (float/int share bit-zero)
__global__ void HeteroGraphSAGE_52931176955955_kernel(float* p, long long n) {
  long long i = (long long)blockIdx.x * 256 + threadIdx.x;
  if (i < n) p[i] = 0.0f;
}

// ---------------- CSR build ----------------
__global__ void g_deg(const int* e, int E, int* deg) {
  int w = blockIdx.x * 256 + threadIdx.x;
  if (w >= E) return;
  atomicAdd(deg + e[E + w], 1);
}

// exclusive prefix over deg[n] -> rp[n+1]; single block, 1024 threads, wave scans
__global__ void g_scan(const int* deg, int* rp, int n) {
  __shared__ int wsum[16];
  __shared__ int base;
  int tid = threadIdx.x;
  int lane = tid & 63;
  int wv = tid >> 6;
  if (tid == 0) { base = 0; rp[0] = 0; }
  __syncthreads();
  for (int start = 0; start < n; start += 1024) {
    int i = start + tid;
    int x = (i < n) ? deg[i] : 0;
    for (int ofs = 1; ofs < 64; ofs <<= 1) {
      int t = __shfl_up(x, ofs);
      if (lane >= ofs) x += t;
    }
    if (lane == 63) wsum[wv] = x;
    __syncthreads();
    if (wv == 0 && lane < 16) {
      int y = wsum[lane];
      for (int ofs = 1; ofs < 16; ofs <<= 1) {
        int t = __shfl_up(y, ofs);
        if (lane >= ofs) y += t;
      }
      wsum[lane] = y;
    }
    __syncthreads();
    int wbase = (wv > 0) ? wsum[wv - 1] : 0;
    if (i < n) rp[i + 1] = base + wbase + x;
    __syncthreads();
    if (tid == 0) base += wsum[15];
    __syncthreads();
  }
}

__global__ void g_fill(const int* e, int E, const int* rp, int* cur, int* col) {
  int w = blockIdx.x * 256 + threadIdx.x;
  if (w >= E) return;
  int s = e[w];
  int d = e[E + w];
  int pos = atomicAdd(cur + d, 1);
  col[rp[d] + pos] = s;
}

// ---------------- fused gather + mean + SAGE GEMM ----------------
// out[r,c] (+)= (1/max(deg,1)) * sum_{s in N(r)} src[s,:] @ Wl[:,c]
//              (+ root[r,:] @ Wr[:,c]) + bias[c]
// block = 256 threads, 16 rows; 8 output rows per thread.
__global__ __launch_bounds__(256) void g_sage(
    const int* rp, const int* col,
    const void* src, int src_bf,
    const void* root, int root_bf,      // root == null -> no root term
    const float* Wl, const float* Wr, const float* bias,
    void* out, int out_bf, int N, int accum) {
  __shared__ float sm[16][128];
  __shared__ float sx[16][128];
  int tid = threadIdx.x;
  int r0 = blockIdx.x * 16;

  for (int i = tid; i < 2048; i += 256) {
    int rr = i >> 7, k = i & 127;
    int row = r0 + rr;
    float mv = 0.f, xv = 0.f;
    if (row < N) {
      int j0 = rp[row], j1 = rp[row + 1];
      for (int j = j0; j < j1; ++j) {
        int s = col[j];
        mv += src_bf ? bf2f(((const u16*)src)[(size_t)s * 128 + k])
                     : ((const float*)src)[(size_t)s * 128 + k];
      }
      mv *= 1.0f / fmaxf((float)(j1 - j0), 1.0f);
      if (root)
        xv = root_bf ? bf2f(((const u16*)root)[(size_t)row * 128 + k])
                     : ((const float*)root)[(size_t)row * 128 + k];
    }
    sm[rr][k] = mv;
    sx[rr][k] = xv;
  }
  __syncthreads();

  int c = tid & 127;
  int h = tid >> 7;  // 0/1 -> rows h*8 .. h*8+7
  float acc[8];
#pragma unroll
  for (int j = 0; j < 8; ++j) acc[j] = 0.f;

  if (root) {
    for (int k = 0; k < 128; ++k) {
      float wl = Wl[k * 128 + c];
      float wr = Wr[k * 128 + c];
#pragma unroll
      for (int j = 0; j < 8; ++j)
        acc[j] += sm[h * 8 + j][k] * wl + sx[h * 8 + j][k] * wr;
    }
  } else {
    for (int k = 0; k < 128; ++k) {
      float wl = Wl[k * 128 + c];
#pragma unroll
      for (int j = 0; j < 8; ++j)
        acc[j] += sm[h * 8 + j][k] * wl;
    }
  }

  float bb = bias[c];
#pragma unroll
  for (int j = 0; j < 8; ++j) {
    int row = r0 + h * 8 + j;
    if (row < N) {
      size_t o = (size_t)row * 128 + c;
      float v = acc[j] + bb;
      if (out_bf) {
        u16* ob = (u16*)out;
        if (accum) v += bf2f(ob[o]);
        ob[o] = f2bf(v);
      } else {
        float* of = (float*)out;
        if (accum) v += of[o];
        of[o] = v;
      }
    }
  }
}

// ---------------- BN (training stats over relu(x)), in-place ----------------
__global__ void g_bnstats(const void* x, int isbf, long long n128, float* stats) {
  long long i0 = (long long)blockIdx.x * 256 + threadIdx.x;
  long long stride = (long long)gridDim.x * 256;
  int c = (int)(i0 & 127);
  float s = 0.f, s2 = 0.f;
  for (long long i = i0; i < n128; i += stride) {
    float v = isbf ? bf2f(((const u16*)x)[i]) : ((const float*)x)[i];
    v = fmaxf(v, 0.f);
    s += v;
    s2 += v * v;
  }
  atomicAdd(stats + c, s);
  atomicAdd(stats + 128 + c, s2);
}

__global__ void g_bnfin(const float* stats, const float* g, const float* b,
                        float invN, float* scsh) {
  int c = threadIdx.x;  // 128
  float m = stats[c] * invN;
  float v = stats[128 + c] * invN - m * m;
  float sc = rsqrtf(v + 1e-5f) * g[c];
  scsh[c] = sc;
  scsh[128 + c] = b[c] - m * sc;
}

__global__ void g_bnapply(void* x, int isbf, const float* scsh, long long n) {
  long long i = (long long)blockIdx.x * 256 + threadIdx.x;
  if (i >= n) return;
  int c = (int)(i & 127);
  if (isbf) {
    u16* xb = (u16*)x;
    xb[i] = f2bf(fmaxf(bf2f(xb[i]), 0.f) * scsh[c] + scsh[128 + c]);
  } else {
    float* xf = (float*)x;
    xf[i] = fmaxf(xf[i], 0.f) * scsh[c] + scsh[128 + c];
  }
}

// ---------------- host helpers ----------------
struct Csr { int* rp; int* col; };

static void build_csr(const int* e, int E, int ndst, Csr c, int* cur, hipStream_t st) {
  HeteroGraphSAGE_52931176955955_kernel<<<nblk4(ndst), 256, 0, st>>>((float*)cur, ndst);
  g_deg<<<nblk4(E), 256, 0, st>>>(e, E, cur);
  g_scan<<<1, 1024, 0, st>>>(cur, c.rp, ndst);
  HeteroGraphSAGE_52931176955955_kernel<<<nblk4(ndst), 256, 0, st>>>((float*)cur, ndst);
  g_fill<<<nblk4(E), 256, 0, st>>>(e, E, c.rp, cur, c.col);
}

static void sage_v4(Csr csr, const void* src, int src_bf, const void* root, int root_bf,
                    const float* Wl, const float* Wr, const float* bias,
                    int ndst, void* out, int out_bf, int accum, hipStream_t st) {
  g_sage<<<(ndst + 15) / 16, 256, 0, st>>>(csr.rp, csr.col, src, src_bf, root, root_bf,
                                           Wl, Wr, bias, out, out_bf, ndst, accum);
}

static void bn_v4(void* h, int isbf, int n, const float* g, const float* b,
                  float* stats, float* scsh, hipStream_t st) {
  HeteroGraphSAGE_52931176955955_kernel<<<1, 256, 0, st>>>(stats, 256);
  g_bnstats<<<1024, 256, 0, st>>>(h, isbf, (long long)n * 128, stats);
  g_bnfin<<<1, 128, 0, st>>>(stats, g, b, 1.0f / (float)n, scsh);
  g_bnapply<<<nblk4((long long)n * 128), 256, 0, st>>>(h, isbf, scsh, (long long)n * 128);
}

extern "C" void kernel_launch(void* const* d_in, const int* in_sizes, int n_in,
                              void* d_out, int out_size, void* d_ws, size_t ws_size,
                              hipStream_t stream) {
  const float* x_paper  = (const float*)d_in[0];
  const float* x_author = (const float*)d_in[1];
  const int* e_pp = (const int*)d_in[3];
  const int* e_pa = (const int*)d_in[4];
  const int* e_ap = (const int*)d_in[5];
  const int* e_ai = (const int*)d_in[6];
  const int* e_ia = (const int*)d_in[7];
  const float* Wl  = (const float*)d_in[8];
  const float* bL  = (const float*)d_in[9];
  const float* Wr  = (const float*)d_in[10];
  const float* bng = (const float*)d_in[11];
  const float* bnb = (const float*)d_in[12];

  const int NP = in_sizes[0] / 128;
  const int NA = in_sizes[1] / 128;
  const int NI = in_sizes[2] / 128;
  const int Epp = in_sizes[3] / 2;
  const int Epa = in_sizes[4] / 2;
  const int Eap = in_sizes[5] / 2;
  const int Eai = in_sizes[6] / 2;
  const int Eia = in_sizes[7] / 2;

  // ws (~101 MB): bf16 h_p1/h_a1 | 5x CSR | cursor | stats | scsh
  char* ws = (char*)d_ws;
  size_t off = 0;
  u16* h_p1 = (u16*)(ws + off);   off += (size_t)NP * 256;
  u16* h_a1 = (u16*)(ws + off);   off += (size_t)NA * 256;
  Csr cpp; cpp.rp = (int*)(ws + off); off += (size_t)(NP + 1) * 4;
  Csr cpa; cpa.rp = (int*)(ws + off); off += (size_t)(NA + 1) * 4;
  Csr cap; cap.rp = (int*)(ws + off); off += (size_t)(NP + 1) * 4;
  Csr cai; cai.rp = (int*)(ws + off); off += (size_t)(NI + 1) * 4;
  Csr cia; cia.rp = (int*)(ws + off); off += (size_t)(NA + 1) * 4;
  cpp.col = (int*)(ws + off); off += (size_t)Epp * 4;
  cpa.col = (int*)(ws + off); off += (size_t)Epa * 4;
  cap.col = (int*)(ws + off); off += (size_t)Eap * 4;
  cai.col = (int*)(ws + off); off += (size_t)Eai * 4;
  cia.col = (int*)(ws + off); off += (size_t)Eia * 4;
  int* cur = (int*)(ws + off);    off += (size_t)NP * 4;
  float* stats = (float*)(ws + off); off += 1024;
  float* scsh  = (float*)(ws + off); off += 1024;

  // d_out fp32: p2 | a2 | i2; layer-0/1 hiddens borrow these regions
  float* outp = (float*)d_out;
  float* outa = outp + (size_t)NP * 128;
  float* outi = outa + (size_t)NA * 128;
  float* h_p0 = outp;
  float* h_a0 = outa;
  float* h_i1 = outi;

  // ---- build CSRs once (reused across layers) ----
  build_csr(e_pp, Epp, NP, cpp, cur, stream);
  build_csr(e_pa, Epa, NA, cpa, cur, stream);
  build_csr(e_ap, Eap, NP, cap, cur, stream);
  build_csr(e_ai, Eai, NI, cai, cur, stream);
  build_csr(e_ia, Eia, NA, cia, cur, stream);

  const void* nul = (const void*)0;

  // ---- Layer 0 ----
  sage_v4(cpp, x_paper, 0, x_paper, 0, Wl + 0 * 16384, Wr + 0 * 16384, bL + 0 * 128,
          NP, h_p0, 0, 0, stream);
  bn_v4(h_p0, 0, NP, bng + 0 * 128, bnb + 0 * 128, stats, scsh, stream);
  sage_v4(cpa, x_paper, 0, x_author, 0, Wl + 1 * 16384, Wr + 1 * 16384, bL + 1 * 128,
          NA, h_a0, 0, 0, stream);
  bn_v4(h_a0, 0, NA, bng + 1 * 128, bnb + 1 * 128, stats, scsh, stream);

  // ---- Layer 1 ----
  sage_v4(cpp, h_p0, 0, h_p0, 0, Wl + 2 * 16384, Wr + 2 * 16384, bL + 2 * 128,
          NP, h_p1, 1, 0, stream);
  sage_v4(cap, h_a0, 0, h_p0, 0, Wl + 4 * 16384, Wr + 4 * 16384, bL + 4 * 128,
          NP, h_p1, 1, 1, stream);
  bn_v4(h_p1, 1, NP, bng + 2 * 128, bnb + 2 * 128, stats, scsh, stream);
  sage_v4(cpa, h_p0, 0, h_a0, 0, Wl + 3 * 16384, Wr + 3 * 16384, bL + 3 * 128,
          NA, h_a1, 1, 0, stream);
  bn_v4(h_a1, 1, NA, bng + 3 * 128, bnb + 3 * 128, stats, scsh, stream);
  sage_v4(cai, h_a0, 0, nul, 0, Wl + 5 * 16384, Wr + 5 * 16384, bL + 5 * 128,
          NI, h_i1, 0, 0, stream);
  bn_v4(h_i1, 0, NI, bng + 4 * 128, bnb + 4 * 128, stats, scsh, stream);

  // ---- Layer 2 (ia reads h_i1 before ai overwrites outi; ai self-root is
  //      block-local: each block stages its own rows before writing them) ----
  sage_v4(cpp, h_p1, 1, h_p1, 1, Wl + 6 * 16384, Wr + 6 * 16384, bL + 6 * 128,
          NP, outp, 0, 0, stream);
  sage_v4(cap, h_a1, 1, h_p1, 1, Wl + 8 * 16384, Wr + 8 * 16384, bL + 8 * 128,
          NP, outp, 0, 1, stream);
  sage_v4(cpa, h_p1, 1, h_a1, 1, Wl + 7 * 16384, Wr + 7 * 16384, bL + 7 * 128,
          NA, outa, 0, 0, stream);
  sage_v4(cia, h_i1, 0, h_a1, 1, Wl + 10 * 16384, Wr + 10 * 16384, bL + 10 * 128,
          NA, outa, 0, 1, stream);
  sage_v4(cai, h_a1, 1, h_i1, 0, Wl + 9 * 16384, Wr + 9 * 16384, bL + 9 * 128,
          NI, outi, 0, 0, stream);

  (void)n_in; (void)ws_size; (void)out_size;
}

// Round 13
// 2775.440 us; speedup vs baseline: 2.6301x; 1.8048x over previous
//
#include <hip/hip_runtime.h>

typedef unsigned short u16;
typedef unsigned int u32;
typedef unsigned long long u64;
typedef __attribute__((ext_vector_type(4))) float f32x4;
typedef __attribute__((ext_vector_type(8))) short s16x8;

__device__ __forceinline__ float bf2f(u16 u) {
  union { u32 i; float f; } x;
  x.i = ((u32)u) << 16;
  return x.f;
}
__device__ __forceinline__ u16 f2bf(float f) {
  union { float f; u32 i; } u;
  u.f = f;
  u32 r = u.i + 0x7fffu + ((u.i >> 16) & 1u);
  return (u16)(r >> 16);
}

static inline int nblk5(long long n) { return (int)((n + 255) / 256); }

// identifier-named symbol; generic zero-fill
__global__ void HeteroGraphSAGE_52931176955955_kernel(float* p, long long n) {
  long long i = (long long)blockIdx.x * 256 + threadIdx.x;
  if (i < n) p[i] = 0.0f;
}

// ---------------- weight prep: WT_bf[w][n][k] = bf16(W[l][k][n]) ----------------
__global__ void g_wprep(const float* Wl, const float* Wr, u16* wt, int total) {
  int idx = blockIdx.x * 256 + threadIdx.x;
  if (idx >= total) return;
  int w = idx >> 14;
  int r = idx & 16383;
  int n = r >> 7, k = r & 127;
  int pair = w / 11, l = w - pair * 11;
  const float* W = pair ? Wr : Wl;
  wt[idx] = f2bf(W[l * 16384 + k * 128 + n]);
}

// ---------------- CSR build ----------------
__global__ void g_deg(const int* e, int E, int* deg) {
  int w = blockIdx.x * 256 + threadIdx.x;
  if (w >= E) return;
  atomicAdd(deg + e[E + w], 1);
}

__global__ void g_scan(const int* deg, int* rp, int n) {
  __shared__ int wsum[16];
  __shared__ int base;
  int tid = threadIdx.x;
  int lane = tid & 63;
  int wv = tid >> 6;
  if (tid == 0) { base = 0; rp[0] = 0; }
  __syncthreads();
  for (int start = 0; start < n; start += 1024) {
    int i = start + tid;
    int x = (i < n) ? deg[i] : 0;
    for (int ofs = 1; ofs < 64; ofs <<= 1) {
      int t = __shfl_up(x, ofs);
      if (lane >= ofs) x += t;
    }
    if (lane == 63) wsum[wv] = x;
    __syncthreads();
    if (wv == 0 && lane < 16) {
      int y = wsum[lane];
      for (int ofs = 1; ofs < 16; ofs <<= 1) {
        int t = __shfl_up(y, ofs);
        if (lane >= ofs) y += t;
      }
      wsum[lane] = y;
    }
    __syncthreads();
    int wbase = (wv > 0) ? wsum[wv - 1] : 0;
    if (i < n) rp[i + 1] = base + wbase + x;
    __syncthreads();
    if (tid == 0) base += wsum[15];
    __syncthreads();
  }
}

__global__ void g_fill(const int* e, int E, const int* rp, int* cur, int* col) {
  int w = blockIdx.x * 256 + threadIdx.x;
  if (w >= E) return;
  int s = e[w];
  int d = e[E + w];
  int pos = atomicAdd(cur + d, 1);
  col[rp[d] + pos] = s;
}

// ---------------- fused gather + mean + MFMA SAGE GEMM ----------------
// out[r,:] (+)= mean_{s in N(r)} src[s,:] @ Wl + root[r,:] @ Wr + bias
// block = 256 thr (4 waves), 16 rows; wave w computes cols [w*32, w*32+32)
__global__ __launch_bounds__(256) void g_sage(
    const int* rp, const int* col,
    const void* src, int src_bf,
    const void* root, int root_bf,
    const u16* wtl, const u16* wtr,     // bf16 W^T, n-major [128][128]
    const float* bias,
    void* out, int out_bf, int N, int accum) {
  __shared__ __align__(16) char smA[8192];   // mean, 16 rows x 512B, swizzled
  __shared__ __align__(16) char smB[8192];   // root
  const int tid = threadIdx.x;
  const int r0 = blockIdx.x * 16;

  // ---- gather + mean + root staging (float4 per thread-chunk) ----
  for (int i = tid; i < 512; i += 256) {
    int rr = i >> 5, q = i & 31;
    int row = r0 + rr;
    float m0 = 0.f, m1 = 0.f, m2 = 0.f, m3 = 0.f;
    float x0 = 0.f, x1 = 0.f, x2 = 0.f, x3 = 0.f;
    if (row < N) {
      int j0 = rp[row], j1 = rp[row + 1];
      if (src_bf) {
        const u16* sp = (const u16*)src;
        for (int j = j0; j < j1; ++j) {
          u64 v = *(const u64*)(sp + (size_t)col[j] * 128 + q * 4);
          m0 += bf2f((u16)v);
          m1 += bf2f((u16)(v >> 16));
          m2 += bf2f((u16)(v >> 32));
          m3 += bf2f((u16)(v >> 48));
        }
      } else {
        const float* sp = (const float*)src;
        for (int j = j0; j < j1; ++j) {
          f32x4 v = *(const f32x4*)(sp + (size_t)col[j] * 128 + q * 4);
          m0 += v.x; m1 += v.y; m2 += v.z; m3 += v.w;
        }
      }
      float inv = 1.0f / fmaxf((float)(j1 - j0), 1.0f);
      m0 *= inv; m1 *= inv; m2 *= inv; m3 *= inv;
      if (root) {
        if (root_bf) {
          u64 v = *(const u64*)((const u16*)root + (size_t)row * 128 + q * 4);
          x0 = bf2f((u16)v); x1 = bf2f((u16)(v >> 16));
          x2 = bf2f((u16)(v >> 32)); x3 = bf2f((u16)(v >> 48));
        } else {
          f32x4 v = *(const f32x4*)((const float*)root + (size_t)row * 128 + q * 4);
          x0 = v.x; x1 = v.y; x2 = v.z; x3 = v.w;
        }
      }
    }
    int byte = (rr << 9) + (q << 4);
    int swz = byte ^ ((rr & 7) << 4);
    f32x4 mv = {m0, m1, m2, m3};
    f32x4 xv = {x0, x1, x2, x3};
    *(f32x4*)(smA + swz) = mv;
    *(f32x4*)(smB + swz) = xv;
  }
  __syncthreads();

  // ---- MFMA: wave wv -> col tiles {2wv, 2wv+1} ----
  const int lane = tid & 63;
  const int wv = tid >> 6;
  const int mi = lane & 15;
  const int kg = lane >> 4;
  f32x4 acc0 = {0.f, 0.f, 0.f, 0.f};
  f32x4 acc1 = {0.f, 0.f, 0.f, 0.f};

#pragma unroll
  for (int kt = 0; kt < 4; ++kt) {
    int k0 = kt * 32 + kg * 8;
    int base = (mi << 9) + (k0 << 2);
    int msk = (mi & 7) << 4;
    f32x4 alo = *(const f32x4*)(smA + (base ^ msk));
    f32x4 ahi = *(const f32x4*)(smA + ((base + 16) ^ msk));
    s16x8 afm;
    afm[0] = (short)f2bf(alo.x); afm[1] = (short)f2bf(alo.y);
    afm[2] = (short)f2bf(alo.z); afm[3] = (short)f2bf(alo.w);
    afm[4] = (short)f2bf(ahi.x); afm[5] = (short)f2bf(ahi.y);
    afm[6] = (short)f2bf(ahi.z); afm[7] = (short)f2bf(ahi.w);
    s16x8 afx;
    if (root) {
      f32x4 xlo = *(const f32x4*)(smB + (base ^ msk));
      f32x4 xhi = *(const f32x4*)(smB + ((base + 16) ^ msk));
      afx[0] = (short)f2bf(xlo.x); afx[1] = (short)f2bf(xlo.y);
      afx[2] = (short)f2bf(xlo.z); afx[3] = (short)f2bf(xlo.w);
      afx[4] = (short)f2bf(xhi.x); afx[5] = (short)f2bf(xhi.y);
      afx[6] = (short)f2bf(xhi.z); afx[7] = (short)f2bf(xhi.w);
    }
    int cr0 = (wv * 2) * 16 + mi;
    int cr1 = cr0 + 16;
    s16x8 bl0 = *(const s16x8*)(wtl + cr0 * 128 + k0);
    s16x8 bl1 = *(const s16x8*)(wtl + cr1 * 128 + k0);
    acc0 = __builtin_amdgcn_mfma_f32_16x16x32_bf16(afm, bl0, acc0, 0, 0, 0);
    acc1 = __builtin_amdgcn_mfma_f32_16x16x32_bf16(afm, bl1, acc1, 0, 0, 0);
    if (root) {
      s16x8 bx0 = *(const s16x8*)(wtr + cr0 * 128 + k0);
      s16x8 bx1 = *(const s16x8*)(wtr + cr1 * 128 + k0);
      acc0 = __builtin_amdgcn_mfma_f32_16x16x32_bf16(afx, bx0, acc0, 0, 0, 0);
      acc1 = __builtin_amdgcn_mfma_f32_16x16x32_bf16(afx, bx1, acc1, 0, 0, 0);
    }
  }

  // ---- epilogue: C/D col = lane&15, row = (lane>>4)*4 + reg [m89] ----
  int rbase = (lane >> 4) << 2;
#pragma unroll
  for (int t = 0; t < 2; ++t) {
    f32x4 a = t ? acc1 : acc0;
    int c = (wv * 2 + t) * 16 + mi;
    float bb = bias[c];
#pragma unroll
    for (int reg = 0; reg < 4; ++reg) {
      int row = r0 + rbase + reg;
      if (row < N) {
        size_t o = (size_t)row * 128 + c;
        float v = a[reg] + bb;
        if (out_bf) {
          u16* ob = (u16*)out;
          if (accum) v += bf2f(ob[o]);
          ob[o] = f2bf(v);
        } else {
          float* of = (float*)out;
          if (accum) v += of[o];
          of[o] = v;
        }
      }
    }
  }
}

// ---------------- BN (training stats over relu(x)), in-place ----------------
__global__ void g_bnstats(const void* x, int isbf, long long n128, float* stats) {
  long long i0 = (long long)blockIdx.x * 256 + threadIdx.x;
  long long stride = (long long)gridDim.x * 256;
  int c = (int)(i0 & 127);
  float s = 0.f, s2 = 0.f;
  for (long long i = i0; i < n128; i += stride) {
    float v = isbf ? bf2f(((const u16*)x)[i]) : ((const float*)x)[i];
    v = fmaxf(v, 0.f);
    s += v;
    s2 += v * v;
  }
  atomicAdd(stats + c, s);
  atomicAdd(stats + 128 + c, s2);
}

__global__ void g_bnfin(const float* stats, const float* g, const float* b,
                        float invN, float* scsh) {
  int c = threadIdx.x;  // 128
  float m = stats[c] * invN;
  float v = stats[128 + c] * invN - m * m;
  float sc = rsqrtf(v + 1e-5f) * g[c];
  scsh[c] = sc;
  scsh[128 + c] = b[c] - m * sc;
}

// 4 elems per thread
__global__ void g_bnapply(void* x, int isbf, const float* scsh, long long n4) {
  long long i = (long long)blockIdx.x * 256 + threadIdx.x;
  if (i >= n4) return;
  int c0 = (int)((i << 2) & 127);
  if (isbf) {
    u16* xb = (u16*)x + (i << 2);
    u64 v = *(const u64*)xb;
    u64 o = 0;
#pragma unroll
    for (int j = 0; j < 4; ++j) {
      float f = fmaxf(bf2f((u16)(v >> (16 * j))), 0.f) * scsh[c0 + j] + scsh[128 + c0 + j];
      o |= ((u64)f2bf(f)) << (16 * j);
    }
    *(u64*)xb = o;
  } else {
    float* xf = (float*)x + (i << 2);
    f32x4 v = *(const f32x4*)xf;
    f32x4 o;
#pragma unroll
    for (int j = 0; j < 4; ++j) o[j] = fmaxf(v[j], 0.f) * scsh[c0 + j] + scsh[128 + c0 + j];
    *(f32x4*)xf = o;
  }
}

// ---------------- host helpers ----------------
struct Csr { int* rp; int* col; };

static void build_csr(const int* e, int E, int ndst, Csr c, int* cur, hipStream_t st) {
  HeteroGraphSAGE_52931176955955_kernel<<<nblk5(ndst), 256, 0, st>>>((float*)cur, ndst);
  g_deg<<<nblk5(E), 256, 0, st>>>(e, E, cur);
  g_scan<<<1, 1024, 0, st>>>(cur, c.rp, ndst);
  HeteroGraphSAGE_52931176955955_kernel<<<nblk5(ndst), 256, 0, st>>>((float*)cur, ndst);
  g_fill<<<nblk5(E), 256, 0, st>>>(e, E, c.rp, cur, c.col);
}

static void sage_v5(Csr csr, const void* src, int src_bf, const void* root, int root_bf,
                    const u16* wt, int l, const float* bias,
                    int ndst, void* out, int out_bf, int accum, hipStream_t st) {
  g_sage<<<(ndst + 15) / 16, 256, 0, st>>>(
      csr.rp, csr.col, src, src_bf, root, root_bf,
      wt + (size_t)l * 16384, wt + (size_t)(11 + l) * 16384,
      bias, out, out_bf, ndst, accum);
}

static void bn_v5(void* h, int isbf, int n, const float* g, const float* b,
                  float* stats, float* scsh, hipStream_t st) {
  HeteroGraphSAGE_52931176955955_kernel<<<1, 256, 0, st>>>(stats, 256);
  g_bnstats<<<1024, 256, 0, st>>>(h, isbf, (long long)n * 128, stats);
  g_bnfin<<<1, 128, 0, st>>>(stats, g, b, 1.0f / (float)n, scsh);
  g_bnapply<<<nblk5((long long)n * 32), 256, 0, st>>>(h, isbf, scsh, (long long)n * 32);
}

extern "C" void kernel_launch(void* const* d_in, const int* in_sizes, int n_in,
                              void* d_out, int out_size, void* d_ws, size_t ws_size,
                              hipStream_t stream) {
  const float* x_paper  = (const float*)d_in[0];
  const float* x_author = (const float*)d_in[1];
  const int* e_pp = (const int*)d_in[3];
  const int* e_pa = (const int*)d_in[4];
  const int* e_ap = (const int*)d_in[5];
  const int* e_ai = (const int*)d_in[6];
  const int* e_ia = (const int*)d_in[7];
  const float* Wl  = (const float*)d_in[8];
  const float* bL  = (const float*)d_in[9];
  const float* Wr  = (const float*)d_in[10];
  const float* bng = (const float*)d_in[11];
  const float* bnb = (const float*)d_in[12];

  const int NP = in_sizes[0] / 128;
  const int NA = in_sizes[1] / 128;
  const int NI = in_sizes[2] / 128;
  const int Epp = in_sizes[3] / 2;
  const int Epa = in_sizes[4] / 2;
  const int Eap = in_sizes[5] / 2;
  const int Eai = in_sizes[6] / 2;
  const int Eia = in_sizes[7] / 2;

  // ws (~102 MB): bf16 h_p1/h_a1 | bf16 W^T | 5x CSR | cursor | stats | scsh
  char* ws = (char*)d_ws;
  size_t off = 0;
  u16* h_p1 = (u16*)(ws + off);   off += (size_t)NP * 256;
  u16* h_a1 = (u16*)(ws + off);   off += (size_t)NA * 256;
  u16* wt   = (u16*)(ws + off);   off += (size_t)22 * 16384 * 2;
  Csr cpp; cpp.rp = (int*)(ws + off); off += (size_t)(NP + 1) * 4;
  Csr cpa; cpa.rp = (int*)(ws + off); off += (size_t)(NA + 1) * 4;
  Csr cap; cap.rp = (int*)(ws + off); off += (size_t)(NP + 1) * 4;
  Csr cai; cai.rp = (int*)(ws + off); off += (size_t)(NI + 1) * 4;
  Csr cia; cia.rp = (int*)(ws + off); off += (size_t)(NA + 1) * 4;
  cpp.col = (int*)(ws + off); off += (size_t)Epp * 4;
  cpa.col = (int*)(ws + off); off += (size_t)Epa * 4;
  cap.col = (int*)(ws + off); off += (size_t)Eap * 4;
  cai.col = (int*)(ws + off); off += (size_t)Eai * 4;
  cia.col = (int*)(ws + off); off += (size_t)Eia * 4;
  int* cur = (int*)(ws + off);    off += (size_t)NP * 4;
  float* stats = (float*)(ws + off); off += 1024;
  float* scsh  = (float*)(ws + off); off += 1024;

  float* outp = (float*)d_out;
  float* outa = outp + (size_t)NP * 128;
  float* outi = outa + (size_t)NA * 128;
  float* h_p0 = outp;
  float* h_a0 = outa;
  float* h_i1 = outi;

  g_wprep<<<nblk5(22 * 16384), 256, 0, stream>>>(Wl, Wr, wt, 22 * 16384);
  build_csr(e_pp, Epp, NP, cpp, cur, stream);
  build_csr(e_pa, Epa, NA, cpa, cur, stream);
  build_csr(e_ap, Eap, NP, cap, cur, stream);
  build_csr(e_ai, Eai, NI, cai, cur, stream);
  build_csr(e_ia, Eia, NA, cia, cur, stream);

  const void* nul = (const void*)0;

  // ---- Layer 0 ----
  sage_v5(cpp, x_paper, 0, x_paper, 0, wt, 0, bL + 0 * 128, NP, h_p0, 0, 0, stream);
  bn_v5(h_p0, 0, NP, bng + 0 * 128, bnb + 0 * 128, stats, scsh, stream);
  sage_v5(cpa, x_paper, 0, x_author, 0, wt, 1, bL + 1 * 128, NA, h_a0, 0, 0, stream);
  bn_v5(h_a0, 0, NA, bng + 1 * 128, bnb + 1 * 128, stats, scsh, stream);

  // ---- Layer 1 ----
  sage_v5(cpp, h_p0, 0, h_p0, 0, wt, 2, bL + 2 * 128, NP, h_p1, 1, 0, stream);
  sage_v5(cap, h_a0, 0, h_p0, 0, wt, 4, bL + 4 * 128, NP, h_p1, 1, 1, stream);
  bn_v5(h_p1, 1, NP, bng + 2 * 128, bnb + 2 * 128, stats, scsh, stream);
  sage_v5(cpa, h_p0, 0, h_a0, 0, wt, 3, bL + 3 * 128, NA, h_a1, 1, 0, stream);
  bn_v5(h_a1, 1, NA, bng + 3 * 128, bnb + 3 * 128, stats, scsh, stream);
  sage_v5(cai, h_a0, 0, nul, 0, wt, 5, bL + 5 * 128, NI, h_i1, 0, 0, stream);
  bn_v5(h_i1, 0, NI, bng + 4 * 128, bnb + 4 * 128, stats, scsh, stream);

  // ---- Layer 2 (ia reads h_i1 before ai overwrites outi; ai root self-alias
  //      is block-local: rows staged to LDS before being written) ----
  sage_v5(cpp, h_p1, 1, h_p1, 1, wt, 6, bL + 6 * 128, NP, outp, 0, 0, stream);
  sage_v5(cap, h_a1, 1, h_p1, 1, wt, 8, bL + 8 * 128, NP, outp, 0, 1, stream);
  sage_v5(cpa, h_p1, 1, h_a1, 1, wt, 7, bL + 7 * 128, NA, outa, 0, 0, stream);
  sage_v5(cia, h_i1, 0, h_a1, 1, wt, 10, bL + 10 * 128, NA, outa, 0, 1, stream);
  sage_v5(cai, h_a1, 1, h_i1, 0, wt, 9, bL + 9 * 128, NI, outi, 0, 0, stream);

  (void)n_in; (void)ws_size; (void)out_size;
}